// Round 11
// baseline (2621.171 us; speedup 1.0000x reference)
//
#include <hip/hip_runtime.h>
#include <hip/hip_bf16.h>

// ---------------------------------------------------------------------------
// Problem constants (reference: B,N,T,P,H = 256,101,128,4,16)
// ---------------------------------------------------------------------------
constexpr int B = 256;
constexpr int N = 101;
constexpr int T = 128;

typedef float vf2 __attribute__((ext_vector_type(2)));
typedef short s8v __attribute__((ext_vector_type(8)));    // 8 bf16 (4 VGPRs)
typedef unsigned short u8v __attribute__((ext_vector_type(8)));
typedef float f4v __attribute__((ext_vector_type(4)));    // MFMA accum

__device__ __forceinline__ float frcp(float x) { return __builtin_amdgcn_rcpf(x); }
__device__ __forceinline__ float sigmoidf_(float x) { return frcp(1.f + __expf(-x)); }
__device__ __forceinline__ float tanhf_(float x) { return 2.f * frcp(1.f + __expf(-2.f * x)) - 1.f; }

// fp32 -> bf16 bits, round-nearest-even
__device__ __forceinline__ unsigned short f2bf(float x) {
  unsigned int u = __float_as_uint(x);
  u = (u + 0x7FFFu + ((u >> 16) & 1u)) >> 16;
  return (unsigned short)u;
}
__device__ __forceinline__ float bf2f(unsigned short u) {
  return __uint_as_float((unsigned int)u << 16);
}

// XCD-aware n-swizzle (R7: cut cc FETCH 605->140 MB). Bijection on [0,101).
__device__ __forceinline__ int swz_n(int L) {
  int q = L & 7, r = L >> 3;
  return q * 13 - (q > 5 ? (q - 5) : 0) + r;
}

// ---------------------------------------------------------------------------
// K1: LSTM. One wave per block; 16 lanes per row-pair (vf2-packed rows).
// R11: h exchanged through a per-wave LDS array (1 ds_write_b64 + 8
// broadcast ds_read_b128 per step) instead of 32 ds_bpermute shfls —
// the shfl version was DS-pipe bound (~32 DS instr/step, VALUBusy 52%).
// ---------------------------------------------------------------------------
__global__ __launch_bounds__(64) void lstm_kernel(
    const float* __restrict__ x, const float* __restrict__ pw,
    const float* __restrict__ pb, const float* __restrict__ w_ih,
    const float* __restrict__ w_hh, const float* __restrict__ b_ih,
    const float* __restrict__ b_hh, float* __restrict__ h_out) {
  __shared__ vf2 sh[4][16];  // [sub][unit] -> (rowA, rowB)
  const int lane = threadIdx.x;
  const int sub = lane >> 4;   // row-pair within wave (0..3)
  const int k = lane & 15;     // hidden unit owned by this lane
  const int row = blockIdx.x * 8 + sub * 2;  // 3232*8 = 25856

  float wih[4][4], whh[4][16], bias[4];
#pragma unroll
  for (int q = 0; q < 4; q++) {
    const int j = q * 16 + k;  // gate order i,f,g,o
    bias[q] = b_ih[j] + b_hh[j];
#pragma unroll
    for (int jj = 0; jj < 4; jj++) wih[q][jj] = w_ih[j * 4 + jj];
#pragma unroll
    for (int m = 0; m < 16; m++) whh[q][m] = w_hh[j * 16 + m];
  }
  float pwr[16], pbr[4];
#pragma unroll
  for (int i = 0; i < 16; i++) pwr[i] = pw[i];
#pragma unroll
  for (int i = 0; i < 4; i++) pbr[i] = pb[i];

  vf2 h = {0.f, 0.f}, c = {0.f, 0.f};
  sh[sub][k] = h;
  const float4* xpA = (const float4*)x + (size_t)row * T;
  const float4* xpB = xpA + T;

#pragma unroll 1
  for (int t = 0; t < T; t++) {
    __syncthreads();  // previous step's h visible (single-wave: ~free)
    float4 xa = xpA[t];
    float4 xb = xpB[t];
    vf2 xv[4];
#pragma unroll
    for (int j = 0; j < 4; j++) {
      vf2 v = {pbr[j], pbr[j]};
      v += pwr[j * 4 + 0] * (vf2){xa.x, xb.x};
      v += pwr[j * 4 + 1] * (vf2){xa.y, xb.y};
      v += pwr[j * 4 + 2] * (vf2){xa.z, xb.z};
      v += pwr[j * 4 + 3] * (vf2){xa.w, xb.w};
      xv[j] = v;
    }
    vf2 a0 = {bias[0], bias[0]}, a1 = {bias[1], bias[1]};
    vf2 a2 = {bias[2], bias[2]}, a3 = {bias[3], bias[3]};
#pragma unroll
    for (int j = 0; j < 4; j++) {
      a0 += wih[0][j] * xv[j];
      a1 += wih[1][j] * xv[j];
      a2 += wih[2][j] * xv[j];
      a3 += wih[3][j] * xv[j];
    }
#pragma unroll
    for (int mm = 0; mm < 4; mm++) {  // 4 vf2 per chunk -> 2x ds_read_b128
      vf2 hm0 = sh[sub][mm * 4 + 0];
      vf2 hm1 = sh[sub][mm * 4 + 1];
      vf2 hm2 = sh[sub][mm * 4 + 2];
      vf2 hm3 = sh[sub][mm * 4 + 3];
      a0 += whh[0][mm * 4 + 0] * hm0 + whh[0][mm * 4 + 1] * hm1 +
            whh[0][mm * 4 + 2] * hm2 + whh[0][mm * 4 + 3] * hm3;
      a1 += whh[1][mm * 4 + 0] * hm0 + whh[1][mm * 4 + 1] * hm1 +
            whh[1][mm * 4 + 2] * hm2 + whh[1][mm * 4 + 3] * hm3;
      a2 += whh[2][mm * 4 + 0] * hm0 + whh[2][mm * 4 + 1] * hm1 +
            whh[2][mm * 4 + 2] * hm2 + whh[2][mm * 4 + 3] * hm3;
      a3 += whh[3][mm * 4 + 0] * hm0 + whh[3][mm * 4 + 1] * hm1 +
            whh[3][mm * 4 + 2] * hm2 + whh[3][mm * 4 + 3] * hm3;
    }
    vf2 ig, fg, gg, og, tc;
    ig.x = sigmoidf_(a0.x); ig.y = sigmoidf_(a0.y);
    fg.x = sigmoidf_(a1.x); fg.y = sigmoidf_(a1.y);
    gg.x = tanhf_(a2.x);    gg.y = tanhf_(a2.y);
    og.x = sigmoidf_(a3.x); og.y = sigmoidf_(a3.y);
    c = fg * c + ig * gg;
    tc.x = tanhf_(c.x);     tc.y = tanhf_(c.y);
    h = og * tc;
    __syncthreads();  // all reads of old h done before overwrite
    sh[sub][k] = h;
  }
  h_out[(size_t)row * 16 + k] = h.x;
  h_out[(size_t)(row + 1) * 16 + k] = h.y;
}

// ---------------------------------------------------------------------------
// Prep: pack cc conv weights into MFMA A-fragment order (bf16). Unchanged.
// ---------------------------------------------------------------------------
__global__ void prep_kernel(const float* __restrict__ t1c,
                            const float* __restrict__ t2c,
                            const float* __restrict__ t3c,
                            unsigned short* __restrict__ apk) {
  const int L = threadIdx.x;  // 64 threads
  const int co = L & 15, q = L >> 4;
#pragma unroll 1
  for (int set = 0; set < 15; set++) {
    int s, p;
    if (set < 3) { s = 0; p = set; }
    else if (set < 9) { s = 1; p = set - 3; }
    else { s = 2; p = set - 9; }
    u8v f;
#pragma unroll
    for (int j = 0; j < 8; j++) {
      float val = 0.f;
      if (s == 0) {
        int dn = p * 4 + q, ci = j;
        if (co < 8 && dn < 11) val = t1c[(co * 8 + ci) * 11 + dn];
      } else {
        int dn = p * 2 + (q >> 1), ci = (q & 1) * 8 + j;
        const float* w = (s == 1) ? t2c : t3c;
        if (dn < 11) val = w[(co * 16 + ci) * 11 + dn];
      }
      f[j] = f2bf(val);
    }
    *(u8v*)&apk[(set * 64 + L) * 8] = f;
  }
}

// ---------------------------------------------------------------------------
// K2/K4/K6: fused d1(relu)+d2(relu), causal dilated 1x3. Streaming.
// Input: raw x fp32 (FIRST) or bf16 planar H [by][ci][N][T].
// Output: bf16 channel-interleaved [by][n][t][CO] for MFMA cc.
// ---------------------------------------------------------------------------
template <int CI, int CO, int DIL, bool FIRST>
__global__ __launch_bounds__(128) void d12_kernel(
    const void* __restrict__ xin,
    const float* __restrict__ pw, const float* __restrict__ pb,
    const float* __restrict__ w1, const float* __restrict__ w2,
    unsigned short* __restrict__ out, int b0) {
  const int t = threadIdx.x;
  const int n = swz_n(blockIdx.x), by = blockIdx.y;

  float r1[3][CO];
#pragma unroll
  for (int u = 0; u < 3; u++)
#pragma unroll
    for (int co = 0; co < CO; co++) r1[u][co] = 0.f;

  if constexpr (FIRST) {
    const int b = b0 + by;
    const float4* xp = (const float4*)xin + ((size_t)b * N + n) * T;
    float px[5][4];
#pragma unroll
    for (int v = 0; v < 5; v++) {
      int idx = t - v * DIL;
      float4 xr = xp[idx < 0 ? 0 : idx];
      bool ok = idx >= 0;
      px[v][0] = ok ? pb[0] + pw[0] * xr.x + pw[1] * xr.y + pw[2] * xr.z + pw[3] * xr.w : 0.f;
      px[v][1] = ok ? pb[1] + pw[4] * xr.x + pw[5] * xr.y + pw[6] * xr.z + pw[7] * xr.w : 0.f;
      px[v][2] = ok ? pb[2] + pw[8] * xr.x + pw[9] * xr.y + pw[10] * xr.z + pw[11] * xr.w : 0.f;
      px[v][3] = ok ? pb[3] + pw[12] * xr.x + pw[13] * xr.y + pw[14] * xr.z + pw[15] * xr.w : 0.f;
    }
#pragma unroll
    for (int ci = 0; ci < CI; ci++) {
#pragma unroll
      for (int j = 0; j < 3; j++) {
#pragma unroll
        for (int co = 0; co < CO; co++) {
          float w = w1[(co * CI + ci) * 3 + j];
#pragma unroll
          for (int u = 0; u < 3; u++) r1[u][co] += w * px[u + 2 - j][ci];
        }
      }
    }
  } else {
#pragma unroll
    for (int ci = 0; ci < CI; ci++) {
      const unsigned short* xp =
          (const unsigned short*)xin + (((size_t)by * CI + ci) * N + n) * T;
      float xt[5];
#pragma unroll
      for (int v = 0; v < 5; v++) {
        int idx = t - v * DIL;
        unsigned short u = xp[idx < 0 ? 0 : idx];
        xt[v] = (idx >= 0) ? bf2f(u) : 0.f;
      }
#pragma unroll
      for (int j = 0; j < 3; j++) {
#pragma unroll
        for (int co = 0; co < CO; co++) {
          float w = w1[(co * CI + ci) * 3 + j];
#pragma unroll
          for (int u = 0; u < 3; u++) r1[u][co] += w * xt[u + 2 - j];
        }
      }
    }
  }

#pragma unroll
  for (int u = 0; u < 3; u++)
#pragma unroll
    for (int co = 0; co < CO; co++) r1[u][co] = fmaxf(r1[u][co], 0.f);

  float acc[CO];
#pragma unroll
  for (int co = 0; co < CO; co++) acc[co] = 0.f;
#pragma unroll
  for (int cm = 0; cm < CO; cm++) {
#pragma unroll
    for (int j = 0; j < 3; j++) {
#pragma unroll
      for (int co = 0; co < CO; co++)
        acc[co] += w2[(co * CO + cm) * 3 + j] * r1[2 - j][cm];
    }
  }
  unsigned short* op = &out[(((size_t)by * N + n) * T + t) * CO];
#pragma unroll
  for (int c8 = 0; c8 < CO / 8; c8++) {
    u8v a;
#pragma unroll
    for (int j = 0; j < 8; j++) a[j] = f2bf(fmaxf(acc[c8 * 8 + j], 0.f));
    *(u8v*)&op[c8 * 8] = a;
  }
}

// ---------------------------------------------------------------------------
// K3/K5/K7: cross-stock 11x1 conv via MFMA (D = 16co x 16t per wave).
// Output & residual intermediates now bf16 planar [by][co][n][t].
// RESMODE: 0 = x-proj+rw (fp32 x), 1 = rw from bf16 H, 2 = identity bf16 H.
// ---------------------------------------------------------------------------
template <int C, int CIR, int RESMODE>
__global__ __launch_bounds__(64) void ccm_kernel(
    const unsigned short* __restrict__ zin,  // [Bc][N][T][C] bf16
    const unsigned short* __restrict__ apk,  // [NMF][64][8] bf16
    const void* __restrict__ resin,          // RESMODE 0: fp32 x; else bf16
    const float* __restrict__ rw,
    const float* __restrict__ pw, const float* __restrict__ pb,
    unsigned short* __restrict__ out,        // bf16 planar [Bc][C][N][T]
    int b0) {
  constexpr int NMF = (C == 8) ? 3 : 6;
  const int L = threadIdx.x;
  const int tcol = L & 15, q = L >> 4;
  const int n = swz_n(blockIdx.x);
  const int t = blockIdx.y * 16 + tcol;
  const int by = blockIdx.z;
  const int b = b0 + by;

  f4v d = {0.f, 0.f, 0.f, 0.f};
#pragma unroll
  for (int p = 0; p < NMF; p++) {
    int dn = (C == 8) ? (p * 4 + q) : (p * 2 + (q >> 1));
    int row = n + dn - 5;
    bool ok = (unsigned)row < (unsigned)N;
    int rowc = ok ? row : 0;
    const unsigned short* bp =
        &zin[(((size_t)by * N + rowc) * T + t) * C + ((C == 16) ? (q & 1) * 8 : 0)];
    s8v bfrag = *(const s8v*)bp;
    if (!ok) bfrag = (s8v){0, 0, 0, 0, 0, 0, 0, 0};
    s8v afrag = *(const s8v*)&apk[(p * 64 + L) * 8];
    d = __builtin_amdgcn_mfma_f32_16x16x32_bf16(afrag, bfrag, d, 0, 0, 0);
  }

  if (C == 8 && q >= 2) return;  // rows 8..15 unused for C=8

  float y[4];
  if constexpr (RESMODE == 0) {
    float4 xr = ((const float4*)resin)[((size_t)b * N + n) * T + t];
    float xv[4];
#pragma unroll
    for (int j = 0; j < 4; j++)
      xv[j] = pb[j] + pw[j * 4 + 0] * xr.x + pw[j * 4 + 1] * xr.y +
              pw[j * 4 + 2] * xr.z + pw[j * 4 + 3] * xr.w;
#pragma unroll
    for (int r = 0; r < 4; r++) {
      int co = q * 4 + r;
      float rv = rw[co * 4 + 0] * xv[0] + rw[co * 4 + 1] * xv[1] +
                 rw[co * 4 + 2] * xv[2] + rw[co * 4 + 3] * xv[3];
      y[r] = fmaxf(rv + fmaxf(d[r], 0.f), 0.f);
    }
  } else if constexpr (RESMODE == 1) {
    const unsigned short* rp = (const unsigned short*)resin;
    float hv[CIR];
#pragma unroll
    for (int ci = 0; ci < CIR; ci++)
      hv[ci] = bf2f(rp[(((size_t)by * CIR + ci) * N + n) * T + t]);
#pragma unroll
    for (int r = 0; r < 4; r++) {
      int co = q * 4 + r;
      float rv = 0.f;
#pragma unroll
      for (int ci = 0; ci < CIR; ci++) rv += rw[co * CIR + ci] * hv[ci];
      y[r] = fmaxf(rv + fmaxf(d[r], 0.f), 0.f);
    }
  } else {
    const unsigned short* rp = (const unsigned short*)resin;
#pragma unroll
    for (int r = 0; r < 4; r++) {
      int co = q * 4 + r;
      float rv = bf2f(rp[(((size_t)by * C + co) * N + n) * T + t]);
      y[r] = fmaxf(rv + fmaxf(d[r], 0.f), 0.f);
    }
  }
#pragma unroll
  for (int r = 0; r < 4; r++) {
    int co = q * 4 + r;
    out[(((size_t)by * C + co) * N + n) * T + t] = f2bf(y[r]);
  }
}

// ---------------------------------------------------------------------------
// conv4: h4[b][o][n] = relu(sum_{ci,t} w4[o][ci][t] * Y[ci][t]).
// One 64-lane wave per (b,n); Y bf16 planar. Streaming.
// ---------------------------------------------------------------------------
__global__ __launch_bounds__(64) void conv4_kernel(
    const unsigned short* __restrict__ Y,  // [Bc][16][N][T] bf16
    const float* __restrict__ w4,          // [16][16][T]
    float* __restrict__ h4,                // [B][16][N]
    int b0) {
  const int tl = threadIdx.x;
  const int n = swz_n(blockIdx.x), by = blockIdx.y;
  const int b = b0 + by;
  const int t0 = tl * 2;

  vf2 y[16];
#pragma unroll
  for (int ci = 0; ci < 16; ci++) {
    unsigned int u =
        *(const unsigned int*)&Y[(((size_t)by * 16 + ci) * N + n) * T + t0];
    y[ci] = (vf2){bf2f((unsigned short)(u & 0xffffu)),
                  bf2f((unsigned short)(u >> 16))};
  }

#pragma unroll 1
  for (int o = 0; o < 16; o++) {
    vf2 s = (vf2)0.f;
#pragma unroll
    for (int ci = 0; ci < 16; ci++) {
      vf2 w = *(const vf2*)&w4[(size_t)(o * 16 + ci) * T + t0];
      s += w * y[ci];
    }
    float sum = s.x + s.y;
    sum += __shfl_down(sum, 32);
    sum += __shfl_down(sum, 16);
    sum += __shfl_down(sum, 8);
    sum += __shfl_down(sum, 4);
    sum += __shfl_down(sum, 2);
    sum += __shfl_down(sum, 1);
    if (tl == 0) h4[((size_t)b * 16 + o) * N + n] = fmaxf(sum, 0.f);
  }
}

// ---------------------------------------------------------------------------
// K8: logits (torch reshape scramble) + softmax over N
// ---------------------------------------------------------------------------
__global__ __launch_bounds__(128) void final_kernel(
    const float* __restrict__ hl, const float* __restrict__ h4,
    const float* __restrict__ ow, const float* __restrict__ ob,
    float* __restrict__ out) {
  __shared__ float red[128];
  int b = blockIdx.x, n = threadIdx.x;
  bool valid = n < N;
  float lv = 0.f;
  if (valid) {
    int idx = b * N + n;
    int sb = idx & (B - 1);
    int sn = idx >> 8;
    const float* h = &hl[((size_t)sb * N + sn) * 16];
    float a = ob[0];
#pragma unroll
    for (int k = 0; k < 16; k++) a += h[k] * ow[k];
#pragma unroll
    for (int c = 0; c < 16; c++) a += h4[((size_t)b * 16 + c) * N + n] * ow[16 + c];
    lv = a;
  }
  red[n] = valid ? lv : -1e30f;
  __syncthreads();
  for (int off = 64; off > 0; off >>= 1) {
    if (n < off) red[n] = fmaxf(red[n], red[n + off]);
    __syncthreads();
  }
  float m = red[0];
  __syncthreads();
  float e = valid ? __expf(lv - m) : 0.f;
  red[n] = e;
  __syncthreads();
  for (int off = 64; off > 0; off >>= 1) {
    if (n < off) red[n] += red[n + off];
    __syncthreads();
  }
  float s = red[0];
  if (valid) out[(size_t)b * N + n] = e / s;
}

// ---------------------------------------------------------------------------
// Launch. Chunked over B. Per-b unit (bf16 intermediates):
// Zb1(8ch) + H1(8ch) + Zb2(16) + H2(16) + Y3(16) bf16 = 32 NT-floats.
// ---------------------------------------------------------------------------
extern "C" void kernel_launch(void* const* d_in, const int* in_sizes, int n_in,
                              void* d_out, int out_size, void* d_ws, size_t ws_size,
                              hipStream_t stream) {
  const float* x    = (const float*)d_in[0];
  const float* pw   = (const float*)d_in[1];
  const float* pb   = (const float*)d_in[2];
  const float* w_ih = (const float*)d_in[3];
  const float* w_hh = (const float*)d_in[4];
  const float* b_ih = (const float*)d_in[5];
  const float* b_hh = (const float*)d_in[6];
  const float* t1d1 = (const float*)d_in[7];
  const float* t1d2 = (const float*)d_in[8];
  const float* t1c  = (const float*)d_in[9];
  const float* t1r  = (const float*)d_in[10];
  const float* t2d1 = (const float*)d_in[11];
  const float* t2d2 = (const float*)d_in[12];
  const float* t2c  = (const float*)d_in[13];
  const float* t2r  = (const float*)d_in[14];
  const float* t3d1 = (const float*)d_in[15];
  const float* t3d2 = (const float*)d_in[16];
  const float* t3c  = (const float*)d_in[17];
  const float* w4   = (const float*)d_in[18];
  const float* ow   = (const float*)d_in[19];
  const float* ob   = (const float*)d_in[20];
  float* outp = (float*)d_out;

  const size_t NT = (size_t)N * T;            // 12928
  const size_t Bn16 = (size_t)B * N * 16;
  const size_t unit = 32 * NT;                // floats per chunked b
  const size_t fixed = 2 * Bn16 + 4096;       // hl + h4 + apk

  int Bc = 4;
  const int cands[7] = {256, 128, 64, 32, 16, 8, 4};
  for (int i = 0; i < 7; i++) {
    if ((cands[i] * unit + fixed) * sizeof(float) <= ws_size) { Bc = cands[i]; break; }
  }

  float* ws = (float*)d_ws;
  float* hl = ws;                              // [B*N][16]
  float* h4 = hl + Bn16;                       // [B][16][N]
  unsigned short* apk = (unsigned short*)(h4 + Bn16);  // 15*64*8 ushorts
  unsigned short* Zb1 = (unsigned short*)(h4 + Bn16 + 4096);  // [Bc][N][T][8]
  unsigned short* H1  = Zb1 + (size_t)Bc * 8 * NT;            // [Bc][8][N][T]
  unsigned short* Zb2 = H1 + (size_t)Bc * 8 * NT;             // [Bc][N][T][16]
  unsigned short* H2  = Zb2 + (size_t)Bc * 16 * NT;           // [Bc][16][N][T]
  unsigned short* Y3  = H2 + (size_t)Bc * 16 * NT;            // [Bc][16][N][T]

  prep_kernel<<<1, 64, 0, stream>>>(t1c, t2c, t3c, apk);
  lstm_kernel<<<(B * N) / 8, 64, 0, stream>>>(x, pw, pb, w_ih, w_hh, b_ih,
                                              b_hh, hl);

  dim3 g(N, Bc);
  dim3 gm(N, T / 16, Bc);
  for (int b0 = 0; b0 < B; b0 += Bc) {
    d12_kernel<4, 8, 1, true>
        <<<g, 128, 0, stream>>>(x, pw, pb, t1d1, t1d2, Zb1, b0);
    ccm_kernel<8, 4, 0><<<gm, 64, 0, stream>>>(
        Zb1, apk + 0 * 512, x, t1r, pw, pb, H1, b0);

    d12_kernel<8, 16, 2, false>
        <<<g, 128, 0, stream>>>(H1, pw, pb, t2d1, t2d2, Zb2, b0);
    ccm_kernel<16, 8, 1><<<gm, 64, 0, stream>>>(
        Zb2, apk + 3 * 512, H1, t2r, pw, pb, H2, b0);

    d12_kernel<16, 16, 4, false>
        <<<g, 128, 0, stream>>>(H2, pw, pb, t3d1, t3d2, Zb2, b0);
    ccm_kernel<16, 16, 2><<<gm, 64, 0, stream>>>(
        Zb2, apk + 9 * 512, H2, nullptr, pw, pb, Y3, b0);

    conv4_kernel<<<g, 64, 0, stream>>>(Y3, w4, h4, b0);
  }

  final_kernel<<<B, 128, 0, stream>>>(hl, h4, ow, ob, outp);
}

// Round 12
// 1468.335 us; speedup vs baseline: 1.7851x; 1.7851x over previous
//
#include <hip/hip_runtime.h>
#include <hip/hip_bf16.h>

// ---------------------------------------------------------------------------
// Problem constants (reference: B,N,T,P,H = 256,101,128,4,16)
// ---------------------------------------------------------------------------
constexpr int B = 256;
constexpr int N = 101;
constexpr int T = 128;

typedef float vf2 __attribute__((ext_vector_type(2)));
typedef short s8v __attribute__((ext_vector_type(8)));    // 8 bf16 (4 VGPRs)
typedef unsigned short u8v __attribute__((ext_vector_type(8)));
typedef float f4v __attribute__((ext_vector_type(4)));    // MFMA accum

__device__ __forceinline__ float frcp(float x) { return __builtin_amdgcn_rcpf(x); }
__device__ __forceinline__ float sigmoidf_(float x) { return frcp(1.f + __expf(-x)); }
__device__ __forceinline__ float tanhf_(float x) { return 2.f * frcp(1.f + __expf(-2.f * x)) - 1.f; }

// fp32 -> bf16 bits, round-nearest-even
__device__ __forceinline__ unsigned short f2bf(float x) {
  unsigned int u = __float_as_uint(x);
  u = (u + 0x7FFFu + ((u >> 16) & 1u)) >> 16;
  return (unsigned short)u;
}

// XCD-aware n-swizzle (R7: cut cc FETCH 605->140 MB). Bijection on [0,101).
__device__ __forceinline__ int swz_n(int L) {
  int q = L & 7, r = L >> 3;
  return q * 13 - (q > 5 ? (q - 5) : 0) + r;
}

// ---------------------------------------------------------------------------
// K1: LSTM (R11 LDS-broadcast version). One wave per block; 16 lanes per
// row-pair (vf2-packed rows). h exchanged via per-wave LDS array.
// ---------------------------------------------------------------------------
__global__ __launch_bounds__(64) void lstm_kernel(
    const float* __restrict__ x, const float* __restrict__ pw,
    const float* __restrict__ pb, const float* __restrict__ w_ih,
    const float* __restrict__ w_hh, const float* __restrict__ b_ih,
    const float* __restrict__ b_hh, float* __restrict__ h_out) {
  __shared__ vf2 sh[4][16];  // [sub][unit] -> (rowA, rowB)
  const int lane = threadIdx.x;
  const int sub = lane >> 4;
  const int k = lane & 15;
  const int row = blockIdx.x * 8 + sub * 2;  // 3232*8 = 25856

  float wih[4][4], whh[4][16], bias[4];
#pragma unroll
  for (int q = 0; q < 4; q++) {
    const int j = q * 16 + k;  // gate order i,f,g,o
    bias[q] = b_ih[j] + b_hh[j];
#pragma unroll
    for (int jj = 0; jj < 4; jj++) wih[q][jj] = w_ih[j * 4 + jj];
#pragma unroll
    for (int m = 0; m < 16; m++) whh[q][m] = w_hh[j * 16 + m];
  }
  float pwr[16], pbr[4];
#pragma unroll
  for (int i = 0; i < 16; i++) pwr[i] = pw[i];
#pragma unroll
  for (int i = 0; i < 4; i++) pbr[i] = pb[i];

  vf2 h = {0.f, 0.f}, c = {0.f, 0.f};
  sh[sub][k] = h;
  const float4* xpA = (const float4*)x + (size_t)row * T;
  const float4* xpB = xpA + T;

#pragma unroll 1
  for (int t = 0; t < T; t++) {
    __syncthreads();
    float4 xa = xpA[t];
    float4 xb = xpB[t];
    vf2 xv[4];
#pragma unroll
    for (int j = 0; j < 4; j++) {
      vf2 v = {pbr[j], pbr[j]};
      v += pwr[j * 4 + 0] * (vf2){xa.x, xb.x};
      v += pwr[j * 4 + 1] * (vf2){xa.y, xb.y};
      v += pwr[j * 4 + 2] * (vf2){xa.z, xb.z};
      v += pwr[j * 4 + 3] * (vf2){xa.w, xb.w};
      xv[j] = v;
    }
    vf2 a0 = {bias[0], bias[0]}, a1 = {bias[1], bias[1]};
    vf2 a2 = {bias[2], bias[2]}, a3 = {bias[3], bias[3]};
#pragma unroll
    for (int j = 0; j < 4; j++) {
      a0 += wih[0][j] * xv[j];
      a1 += wih[1][j] * xv[j];
      a2 += wih[2][j] * xv[j];
      a3 += wih[3][j] * xv[j];
    }
#pragma unroll
    for (int mm = 0; mm < 4; mm++) {
      vf2 hm0 = sh[sub][mm * 4 + 0];
      vf2 hm1 = sh[sub][mm * 4 + 1];
      vf2 hm2 = sh[sub][mm * 4 + 2];
      vf2 hm3 = sh[sub][mm * 4 + 3];
      a0 += whh[0][mm * 4 + 0] * hm0 + whh[0][mm * 4 + 1] * hm1 +
            whh[0][mm * 4 + 2] * hm2 + whh[0][mm * 4 + 3] * hm3;
      a1 += whh[1][mm * 4 + 0] * hm0 + whh[1][mm * 4 + 1] * hm1 +
            whh[1][mm * 4 + 2] * hm2 + whh[1][mm * 4 + 3] * hm3;
      a2 += whh[2][mm * 4 + 0] * hm0 + whh[2][mm * 4 + 1] * hm1 +
            whh[2][mm * 4 + 2] * hm2 + whh[2][mm * 4 + 3] * hm3;
      a3 += whh[3][mm * 4 + 0] * hm0 + whh[3][mm * 4 + 1] * hm1 +
            whh[3][mm * 4 + 2] * hm2 + whh[3][mm * 4 + 3] * hm3;
    }
    vf2 ig, fg, gg, og, tc;
    ig.x = sigmoidf_(a0.x); ig.y = sigmoidf_(a0.y);
    fg.x = sigmoidf_(a1.x); fg.y = sigmoidf_(a1.y);
    gg.x = tanhf_(a2.x);    gg.y = tanhf_(a2.y);
    og.x = sigmoidf_(a3.x); og.y = sigmoidf_(a3.y);
    c = fg * c + ig * gg;
    tc.x = tanhf_(c.x);     tc.y = tanhf_(c.y);
    h = og * tc;
    __syncthreads();
    sh[sub][k] = h;
  }
  h_out[(size_t)row * 16 + k] = h.x;
  h_out[(size_t)(row + 1) * 16 + k] = h.y;
}

// ---------------------------------------------------------------------------
// Prep: pack cc conv weights into MFMA A-fragment order (bf16). Unchanged.
// ---------------------------------------------------------------------------
__global__ void prep_kernel(const float* __restrict__ t1c,
                            const float* __restrict__ t2c,
                            const float* __restrict__ t3c,
                            unsigned short* __restrict__ apk) {
  const int L = threadIdx.x;  // 64 threads
  const int co = L & 15, q = L >> 4;
#pragma unroll 1
  for (int set = 0; set < 15; set++) {
    int s, p;
    if (set < 3) { s = 0; p = set; }
    else if (set < 9) { s = 1; p = set - 3; }
    else { s = 2; p = set - 9; }
    u8v f;
#pragma unroll
    for (int j = 0; j < 8; j++) {
      float val = 0.f;
      if (s == 0) {
        int dn = p * 4 + q, ci = j;
        if (co < 8 && dn < 11) val = t1c[(co * 8 + ci) * 11 + dn];
      } else {
        int dn = p * 2 + (q >> 1), ci = (q & 1) * 8 + j;
        const float* w = (s == 1) ? t2c : t3c;
        if (dn < 11) val = w[(co * 16 + ci) * 11 + dn];
      }
      f[j] = f2bf(val);
    }
    *(u8v*)&apk[(set * 64 + L) * 8] = f;
  }
}

// ---------------------------------------------------------------------------
// K2 (stage 1 only): fused d1+d2, proj folded, fp32 x input, bf16
// channel-interleaved output [by][n][t][8]. R5-proven scalar streaming.
// ---------------------------------------------------------------------------
__global__ __launch_bounds__(128) void d12a_kernel(
    const float* __restrict__ xin,
    const float* __restrict__ pw, const float* __restrict__ pb,
    const float* __restrict__ w1,  // [8][4][3]
    const float* __restrict__ w2,  // [8][8][3]
    unsigned short* __restrict__ out, int b0) {
  constexpr int CI = 4, CO = 8, DIL = 1;
  const int t = threadIdx.x;
  const int n = swz_n(blockIdx.x), by = blockIdx.y;
  const int b = b0 + by;

  float r1[3][CO];
#pragma unroll
  for (int u = 0; u < 3; u++)
#pragma unroll
    for (int co = 0; co < CO; co++) r1[u][co] = 0.f;

  const float4* xp = (const float4*)xin + ((size_t)b * N + n) * T;
  float px[5][4];
#pragma unroll
  for (int v = 0; v < 5; v++) {
    int idx = t - v * DIL;
    float4 xr = xp[idx < 0 ? 0 : idx];
    bool ok = idx >= 0;
    px[v][0] = ok ? pb[0] + pw[0] * xr.x + pw[1] * xr.y + pw[2] * xr.z + pw[3] * xr.w : 0.f;
    px[v][1] = ok ? pb[1] + pw[4] * xr.x + pw[5] * xr.y + pw[6] * xr.z + pw[7] * xr.w : 0.f;
    px[v][2] = ok ? pb[2] + pw[8] * xr.x + pw[9] * xr.y + pw[10] * xr.z + pw[11] * xr.w : 0.f;
    px[v][3] = ok ? pb[3] + pw[12] * xr.x + pw[13] * xr.y + pw[14] * xr.z + pw[15] * xr.w : 0.f;
  }
#pragma unroll
  for (int ci = 0; ci < CI; ci++) {
#pragma unroll
    for (int j = 0; j < 3; j++) {
#pragma unroll
      for (int co = 0; co < CO; co++) {
        float w = w1[(co * CI + ci) * 3 + j];
#pragma unroll
        for (int u = 0; u < 3; u++) r1[u][co] += w * px[u + 2 - j][ci];
      }
    }
  }
#pragma unroll
  for (int u = 0; u < 3; u++)
#pragma unroll
    for (int co = 0; co < CO; co++) r1[u][co] = fmaxf(r1[u][co], 0.f);

  float acc[CO];
#pragma unroll
  for (int co = 0; co < CO; co++) acc[co] = 0.f;
#pragma unroll
  for (int cm = 0; cm < CO; cm++) {
#pragma unroll
    for (int j = 0; j < 3; j++) {
#pragma unroll
      for (int co = 0; co < CO; co++)
        acc[co] += w2[(co * CO + cm) * 3 + j] * r1[2 - j][cm];
    }
  }
  unsigned short* op = &out[(((size_t)by * N + n) * T + t) * CO];
  u8v a;
#pragma unroll
  for (int j = 0; j < 8; j++) a[j] = f2bf(fmaxf(acc[j], 0.f));
  *(u8v*)&op[0] = a;
}

// ---------------------------------------------------------------------------
// K4/K6 (stages 2/3): fused d1+d2, vf2 t-pairs (v_pk_fma_f32), CO grouped
// by 4 to bound the live set (acc2 32 + r1 24 + taps ~20 VGPR -> no spill;
// the R11 version was register-squeezed at VGPR=52 with ~70 live floats).
// Input fp32 planar; output bf16 channel-interleaved [by][n][t][CO].
// DIL must be even (2,4) so t-pair taps stay pair-aligned.
// ---------------------------------------------------------------------------
template <int CI, int CO, int DIL>
__global__ __launch_bounds__(64) void d12v_kernel(
    const float* __restrict__ xin,   // [Bc][CI][N][T] fp32
    const float* __restrict__ w1,    // [CO][CI][3]
    const float* __restrict__ w2,    // [CO][CO][3]
    unsigned short* __restrict__ out) {
  const int tl = threadIdx.x;   // 64 threads, t-pair index
  const int t0 = tl * 2;
  const int n = swz_n(blockIdx.x), by = blockIdx.y;

  vf2 acc2[CO];
#pragma unroll
  for (int co = 0; co < CO; co++) acc2[co] = (vf2)0.f;

#pragma unroll 1
  for (int g = 0; g < CO / 4; g++) {
    vf2 r1[3][4];
#pragma unroll
    for (int u = 0; u < 3; u++)
#pragma unroll
      for (int cq = 0; cq < 4; cq++) r1[u][cq] = (vf2)0.f;

#pragma unroll 2
    for (int ci = 0; ci < CI; ci++) {
      const float* xp = xin + (((size_t)by * CI + ci) * N + n) * T;
      vf2 xt[5];
#pragma unroll
      for (int v = 0; v < 5; v++) {
        int idx = t0 - v * DIL;
        vf2 xv = *(const vf2*)&xp[idx < 0 ? 0 : idx];
        xt[v] = (idx >= 0) ? xv : (vf2)0.f;
      }
#pragma unroll
      for (int j = 0; j < 3; j++) {
#pragma unroll
        for (int cq = 0; cq < 4; cq++) {
          float w = w1[((g * 4 + cq) * CI + ci) * 3 + j];
#pragma unroll
          for (int u = 0; u < 3; u++) r1[u][cq] += w * xt[u + 2 - j];
        }
      }
    }
#pragma unroll
    for (int u = 0; u < 3; u++)
#pragma unroll
      for (int cq = 0; cq < 4; cq++) {
        r1[u][cq].x = fmaxf(r1[u][cq].x, 0.f);
        r1[u][cq].y = fmaxf(r1[u][cq].y, 0.f);
      }
#pragma unroll
    for (int cq = 0; cq < 4; cq++) {
#pragma unroll
      for (int j = 0; j < 3; j++) {
#pragma unroll
        for (int co = 0; co < CO; co++) {
          float w = w2[(co * CO + g * 4 + cq) * 3 + j];
          acc2[co] += w * r1[2 - j][cq];
        }
      }
    }
  }

  // bf16 interleaved store: 2 consecutive t-rows of CO ch = 64 B contiguous
  unsigned short* op = &out[(((size_t)by * N + n) * T + t0) * CO];
#pragma unroll
  for (int c8 = 0; c8 < CO / 8; c8++) {
    u8v a, bvec;
#pragma unroll
    for (int jj = 0; jj < 8; jj++) {
      a[jj] = f2bf(fmaxf(acc2[c8 * 8 + jj].x, 0.f));
      bvec[jj] = f2bf(fmaxf(acc2[c8 * 8 + jj].y, 0.f));
    }
    *(u8v*)&op[c8 * 8] = a;
    *(u8v*)&op[CO + c8 * 8] = bvec;
  }
}

// ---------------------------------------------------------------------------
// K3/K5/K7: cross-stock 11x1 conv via MFMA (R10 version: fp32 out/residual).
// RESMODE: 0 = x-proj+rw (C=8), 1 = rw from fp32 H, 2 = identity fp32 H.
// ---------------------------------------------------------------------------
template <int C, int CIR, int RESMODE>
__global__ __launch_bounds__(64) void ccm_kernel(
    const unsigned short* __restrict__ zin,  // [Bc][N][T][C] bf16
    const unsigned short* __restrict__ apk,  // [NMF][64][8] bf16
    const float* __restrict__ resin,         // RESMODE 0: x; else fp32 planar
    const float* __restrict__ rw,
    const float* __restrict__ pw, const float* __restrict__ pb,
    float* __restrict__ out,                 // fp32 planar [Bc][C][N][T]
    int b0) {
  constexpr int NMF = (C == 8) ? 3 : 6;
  const int L = threadIdx.x;
  const int tcol = L & 15, q = L >> 4;
  const int n = swz_n(blockIdx.x);
  const int t = blockIdx.y * 16 + tcol;
  const int by = blockIdx.z;
  const int b = b0 + by;

  f4v d = {0.f, 0.f, 0.f, 0.f};
#pragma unroll
  for (int p = 0; p < NMF; p++) {
    int dn = (C == 8) ? (p * 4 + q) : (p * 2 + (q >> 1));
    int row = n + dn - 5;
    bool ok = (unsigned)row < (unsigned)N;
    int rowc = ok ? row : 0;
    const unsigned short* bp =
        &zin[(((size_t)by * N + rowc) * T + t) * C + ((C == 16) ? (q & 1) * 8 : 0)];
    s8v bfrag = *(const s8v*)bp;
    if (!ok) bfrag = (s8v){0, 0, 0, 0, 0, 0, 0, 0};
    s8v afrag = *(const s8v*)&apk[(p * 64 + L) * 8];
    d = __builtin_amdgcn_mfma_f32_16x16x32_bf16(afrag, bfrag, d, 0, 0, 0);
  }

  if (C == 8 && q >= 2) return;

  float y[4];
  if constexpr (RESMODE == 0) {
    float4 xr = ((const float4*)resin)[((size_t)b * N + n) * T + t];
    float xv[4];
#pragma unroll
    for (int j = 0; j < 4; j++)
      xv[j] = pb[j] + pw[j * 4 + 0] * xr.x + pw[j * 4 + 1] * xr.y +
              pw[j * 4 + 2] * xr.z + pw[j * 4 + 3] * xr.w;
#pragma unroll
    for (int r = 0; r < 4; r++) {
      int co = q * 4 + r;
      float rv = rw[co * 4 + 0] * xv[0] + rw[co * 4 + 1] * xv[1] +
                 rw[co * 4 + 2] * xv[2] + rw[co * 4 + 3] * xv[3];
      y[r] = fmaxf(rv + fmaxf(d[r], 0.f), 0.f);
    }
  } else if constexpr (RESMODE == 1) {
    float hv[CIR];
#pragma unroll
    for (int ci = 0; ci < CIR; ci++)
      hv[ci] = resin[(((size_t)by * CIR + ci) * N + n) * T + t];
#pragma unroll
    for (int r = 0; r < 4; r++) {
      int co = q * 4 + r;
      float rv = 0.f;
#pragma unroll
      for (int ci = 0; ci < CIR; ci++) rv += rw[co * CIR + ci] * hv[ci];
      y[r] = fmaxf(rv + fmaxf(d[r], 0.f), 0.f);
    }
  } else {
#pragma unroll
    for (int r = 0; r < 4; r++) {
      int co = q * 4 + r;
      float rv = resin[(((size_t)by * C + co) * N + n) * T + t];
      y[r] = fmaxf(rv + fmaxf(d[r], 0.f), 0.f);
    }
  }
#pragma unroll
  for (int r = 0; r < 4; r++) {
    int co = q * 4 + r;
    out[(((size_t)by * C + co) * N + n) * T + t] = y[r];
  }
}

// ---------------------------------------------------------------------------
// conv4: h4[b][o][n] = relu(sum_{ci,t} w4[o][ci][t] * Y[ci][t]).
// One 64-lane wave per (b,n); Y fp32 planar (R10 version).
// ---------------------------------------------------------------------------
__global__ __launch_bounds__(64) void conv4_kernel(
    const float* __restrict__ Y,   // [Bc][16][N][T]
    const float* __restrict__ w4,  // [16][16][T]
    float* __restrict__ h4,        // [B][16][N]
    int b0) {
  const int tl = threadIdx.x;
  const int n = swz_n(blockIdx.x), by = blockIdx.y;
  const int b = b0 + by;
  const int t0 = tl * 2;

  vf2 y[16];
#pragma unroll
  for (int ci = 0; ci < 16; ci++)
    y[ci] = *(const vf2*)&Y[(((size_t)by * 16 + ci) * N + n) * T + t0];

#pragma unroll 1
  for (int o = 0; o < 16; o++) {
    vf2 s = (vf2)0.f;
#pragma unroll
    for (int ci = 0; ci < 16; ci++) {
      vf2 w = *(const vf2*)&w4[(size_t)(o * 16 + ci) * T + t0];
      s += w * y[ci];
    }
    float sum = s.x + s.y;
    sum += __shfl_down(sum, 32);
    sum += __shfl_down(sum, 16);
    sum += __shfl_down(sum, 8);
    sum += __shfl_down(sum, 4);
    sum += __shfl_down(sum, 2);
    sum += __shfl_down(sum, 1);
    if (tl == 0) h4[((size_t)b * 16 + o) * N + n] = fmaxf(sum, 0.f);
  }
}

// ---------------------------------------------------------------------------
// K8: logits (torch reshape scramble) + softmax over N
// ---------------------------------------------------------------------------
__global__ __launch_bounds__(128) void final_kernel(
    const float* __restrict__ hl, const float* __restrict__ h4,
    const float* __restrict__ ow, const float* __restrict__ ob,
    float* __restrict__ out) {
  __shared__ float red[128];
  int b = blockIdx.x, n = threadIdx.x;
  bool valid = n < N;
  float lv = 0.f;
  if (valid) {
    int idx = b * N + n;
    int sb = idx & (B - 1);
    int sn = idx >> 8;
    const float* h = &hl[((size_t)sb * N + sn) * 16];
    float a = ob[0];
#pragma unroll
    for (int k = 0; k < 16; k++) a += h[k] * ow[k];
#pragma unroll
    for (int c = 0; c < 16; c++) a += h4[((size_t)b * 16 + c) * N + n] * ow[16 + c];
    lv = a;
  }
  red[n] = valid ? lv : -1e30f;
  __syncthreads();
  for (int off = 64; off > 0; off >>= 1) {
    if (n < off) red[n] = fmaxf(red[n], red[n + off]);
    __syncthreads();
  }
  float m = red[0];
  __syncthreads();
  float e = valid ? __expf(lv - m) : 0.f;
  red[n] = e;
  __syncthreads();
  for (int off = 64; off > 0; off >>= 1) {
    if (n < off) red[n] += red[n + off];
    __syncthreads();
  }
  float s = red[0];
  if (valid) out[(size_t)b * N + n] = e / s;
}

// ---------------------------------------------------------------------------
// Launch. Chunked over B. Per-b unit: Zb1(bf16 8ch=4) + H1(fp32 8ch=8) +
// Zb2(bf16 16ch=8) + H2(fp32 16) + Y3(fp32 16) = 52 NT-floats.
// ---------------------------------------------------------------------------
extern "C" void kernel_launch(void* const* d_in, const int* in_sizes, int n_in,
                              void* d_out, int out_size, void* d_ws, size_t ws_size,
                              hipStream_t stream) {
  const float* x    = (const float*)d_in[0];
  const float* pw   = (const float*)d_in[1];
  const float* pb   = (const float*)d_in[2];
  const float* w_ih = (const float*)d_in[3];
  const float* w_hh = (const float*)d_in[4];
  const float* b_ih = (const float*)d_in[5];
  const float* b_hh = (const float*)d_in[6];
  const float* t1d1 = (const float*)d_in[7];
  const float* t1d2 = (const float*)d_in[8];
  const float* t1c  = (const float*)d_in[9];
  const float* t1r  = (const float*)d_in[10];
  const float* t2d1 = (const float*)d_in[11];
  const float* t2d2 = (const float*)d_in[12];
  const float* t2c  = (const float*)d_in[13];
  const float* t2r  = (const float*)d_in[14];
  const float* t3d1 = (const float*)d_in[15];
  const float* t3d2 = (const float*)d_in[16];
  const float* t3c  = (const float*)d_in[17];
  const float* w4   = (const float*)d_in[18];
  const float* ow   = (const float*)d_in[19];
  const float* ob   = (const float*)d_in[20];
  float* outp = (float*)d_out;

  const size_t NT = (size_t)N * T;            // 12928
  const size_t Bn16 = (size_t)B * N * 16;
  const size_t unit = 52 * NT;                // floats per chunked b
  const size_t fixed = 2 * Bn16 + 4096;       // hl + h4 + apk

  int Bc = 4;
  const int cands[7] = {256, 128, 64, 32, 16, 8, 4};
  for (int i = 0; i < 7; i++) {
    if ((cands[i] * unit + fixed) * sizeof(float) <= ws_size) { Bc = cands[i]; break; }
  }

  float* ws = (float*)d_ws;
  float* hl = ws;                              // [B*N][16]
  float* h4 = hl + Bn16;                       // [B][16][N]
  unsigned short* apk = (unsigned short*)(h4 + Bn16);  // 15*64*8 ushorts
  float* base = h4 + Bn16 + 4096;
  unsigned short* Zb1 = (unsigned short*)base;            // [Bc][N][T][8] bf16
  float* H1 = base + (size_t)Bc * 4 * NT;                 // [Bc][8][N][T]
  unsigned short* Zb2 = (unsigned short*)(H1 + (size_t)Bc * 8 * NT);  // [Bc][N][T][16]
  float* H2 = H1 + (size_t)Bc * 16 * NT;                  // [Bc][16][N][T]
  float* Y3 = H2 + (size_t)Bc * 16 * NT;                  // [Bc][16][N][T]

  prep_kernel<<<1, 64, 0, stream>>>(t1c, t2c, t3c, apk);
  lstm_kernel<<<(B * N) / 8, 64, 0, stream>>>(x, pw, pb, w_ih, w_hh, b_ih,
                                              b_hh, hl);

  dim3 g(N, Bc);
  dim3 gm(N, T / 16, Bc);
  for (int b0 = 0; b0 < B; b0 += Bc) {
    d12a_kernel<<<g, 128, 0, stream>>>(x, pw, pb, t1d1, t1d2, Zb1, b0);
    ccm_kernel<8, 4, 0><<<gm, 64, 0, stream>>>(
        Zb1, apk + 0 * 512, x, t1r, pw, pb, H1, b0);

    d12v_kernel<8, 16, 2><<<g, 64, 0, stream>>>(H1, t2d1, t2d2, Zb2);
    ccm_kernel<16, 8, 1><<<gm, 64, 0, stream>>>(
        Zb2, apk + 3 * 512, H1, t2r, pw, pb, H2, b0);

    d12v_kernel<16, 16, 4><<<g, 64, 0, stream>>>(H2, t3d1, t3d2, Zb2);
    ccm_kernel<16, 16, 2><<<gm, 64, 0, stream>>>(
        Zb2, apk + 9 * 512, H2, nullptr, pw, pb, Y3, b0);

    conv4_kernel<<<g, 64, 0, stream>>>(Y3, w4, h4, b0);
  }

  final_kernel<<<B, 128, 0, stream>>>(hl, h4, ow, ob, outp);
}